// Round 14
// baseline (1116.220 us; speedup 1.0000x reference)
//
#include <hip/hip_runtime.h>

#define DIN 128
#define HDIM 64
#define SLAB 32
#define OVF_CAP 65536

__device__ __forceinline__ unsigned short f2bf(float f) {
    unsigned u = __float_as_uint(f);
    unsigned r = (u + 0x7fffu + ((u >> 16) & 1u)) >> 16;
    return (unsigned short)r;
}
__device__ __forceinline__ float lo16f(unsigned v) { return __uint_as_float(v << 16); }
__device__ __forceinline__ float hi16f(unsigned v) { return __uint_as_float(v & 0xffff0000u); }

// ---- fused front, parity 1:3 — blockIdx%4==0: scatter 2048 edges (EPT=8);
//      else: 64-node h1 GEMM tile (raw bf16), 16 KB LDS (4 K-chunks).
__global__ __launch_bounds__(256) void k_front(
        const int* __restrict__ src, const int* __restrict__ dst,
        int* __restrict__ cursor, int* __restrict__ slab,
        int* __restrict__ ovf, int* __restrict__ govf, int E, int scBlocks,
        const float* __restrict__ x, const float* __restrict__ W1,
        unsigned short* __restrict__ hs_bf, int n, int gBlocks) {
    __shared__ float4 xs[64 * 8];
    __shared__ float4 ws[64 * 8];
    int t = threadIdx.x;
    int cyc = blockIdx.x >> 2, r = blockIdx.x & 3;

    if (r == 0) {
        // ---------- scatter role: 8 edges/thread ----------
        int sid = cyc;
        if (sid >= scBlocks) return;
        int ebase = sid * 2048 + t;
        int d[8], s[8], p[8];
        bool ok[8];
        #pragma unroll
        for (int q = 0; q < 8; ++q) {
            int e = ebase + q * 256;
            ok[q] = e < E;
            d[q] = ok[q] ? dst[e] : 0;
            s[q] = ok[q] ? src[e] : 0;
        }
        #pragma unroll
        for (int q = 0; q < 8; ++q)
            if (ok[q]) p[q] = atomicAdd(&cursor[d[q]], 1);
        #pragma unroll
        for (int q = 0; q < 8; ++q) {
            if (ok[q]) {
                if (p[q] < SLAB) {
                    slab[(size_t)d[q] * SLAB + p[q]] = s[q];
                } else {
                    int o = atomicAdd(govf, 1);
                    if (o < OVF_CAP) { ovf[2 * o] = d[q]; ovf[2 * o + 1] = s[q]; }
                }
            }
        }
        return;
    }

    // ---------- h1 GEMM role (unscaled): hs_bf = bf16(x @ W1^T) ----------
    int gid = cyc * 3 + (r - 1);
    if (gid >= gBlocks) return;
    int ty = t >> 4, tx = t & 15;
    int nodeBase = gid * 64;
    const float4* W14 = (const float4*)W1;
    const float4* x4 = (const float4*)(x + (size_t)nodeBase * DIN);
    int limf4 = (n - nodeBase) * (DIN / 4);

    float acc[4][4] = {};
    #pragma unroll
    for (int ch = 0; ch < 4; ++ch) {
        if (ch) __syncthreads();
        #pragma unroll
        for (int i = 0; i < 2; ++i) {
            int e = t + i * 256;
            int rr = e >> 3, c4 = e & 7;
            int f4 = rr * 32 + ch * 8 + c4;
            ws[rr * 8 + (c4 ^ (rr & 7))] = W14[f4];
            float4 v = make_float4(0.f, 0.f, 0.f, 0.f);
            if (f4 < limf4) v = x4[f4];
            xs[rr * 8 + (c4 ^ (rr & 7))] = v;
        }
        __syncthreads();
        #pragma unroll
        for (int k4 = 0; k4 < 8; ++k4) {
            float4 xa[4], wb[4];
            #pragma unroll
            for (int i = 0; i < 4; ++i) {
                int rr = ty + 16 * i;
                xa[i] = xs[rr * 8 + (k4 ^ (rr & 7))];
            }
            #pragma unroll
            for (int j = 0; j < 4; ++j) {
                int rr = tx + 16 * j;
                wb[j] = ws[rr * 8 + (k4 ^ (rr & 7))];
            }
            #pragma unroll
            for (int i = 0; i < 4; ++i)
                #pragma unroll
                for (int j = 0; j < 4; ++j)
                    acc[i][j] += xa[i].x * wb[j].x + xa[i].y * wb[j].y +
                                 xa[i].z * wb[j].z + xa[i].w * wb[j].w;
        }
    }
    #pragma unroll
    for (int i = 0; i < 4; ++i) {
        int node = nodeBase + ty + 16 * i;
        if (node < n) {
            #pragma unroll
            for (int j = 0; j < 4; ++j)
                hs_bf[(size_t)node * HDIM + tx + 16 * j] = f2bf(acc[i][j]);
        }
    }
}

// ---- gather, software-pipelined: hoisted slab/cursor loads for 8 nodes,
//      per-edge dinv, in-kernel overflow, bf16 h output ----
__global__ __launch_bounds__(256) void k_gather(const int* __restrict__ cursor,
                                                const int* __restrict__ slab,
                                                const unsigned short* __restrict__ hs_bf,
                                                const int* __restrict__ govf,
                                                const int* __restrict__ ovf,
                                                unsigned short* __restrict__ h_bf, int n) {
    int tid = threadIdx.x;
    int lane = tid & 63, wave = tid >> 6;
    int grp = lane >> 3;   // edge slot within octet
    int w8 = lane & 7;     // feature octet
    const int NPW = 8;
    int base = blockIdx.x * (4 * NPW) + wave * NPW;
    int novf = govf[0];
    if (novf > OVF_CAP) novf = OVF_CAP;

    // Phase A: independent slab + degree loads for all 8 nodes
    int c[NPW], sv[NPW];
    #pragma unroll
    for (int k = 0; k < NPW; ++k) {
        int node = base + k;
        bool valid = node < n;
        c[k] = valid ? cursor[node] : 0;
        int cs = (c[k] < SLAB) ? c[k] : SLAB;
        sv[k] = (valid && lane < cs) ? slab[(size_t)node * SLAB + lane] : 0;
    }
    // Phase B: per-edge source degrees (independent gathers)
    float dnv[NPW];
    #pragma unroll
    for (int k = 0; k < NPW; ++k) {
        int cs = (c[k] < SLAB) ? c[k] : SLAB;
        dnv[k] = (lane < cs) ? rsqrtf((float)cursor[sv[k]] + 1.0f) : 0.f;
    }
    // Phase C: per-node accumulation
    #pragma unroll
    for (int k = 0; k < NPW; ++k) {
        int node = base + k;
        if (node >= n) break;
        int cs = (c[k] < SLAB) ? c[k] : SLAB;
        float dni = rsqrtf((float)c[k] + 1.0f);
        uint4 v0 = *(const uint4*)(hs_bf + ((size_t)node << 6) + 8 * w8);
        float sw = (grp == 0) ? dni : 0.f;
        float a0 = sw * lo16f(v0.x), a1 = sw * hi16f(v0.x);
        float a2 = sw * lo16f(v0.y), a3 = sw * hi16f(v0.y);
        float a4 = sw * lo16f(v0.z), a5 = sw * hi16f(v0.z);
        float a6 = sw * lo16f(v0.w), a7 = sw * hi16f(v0.w);
        int nfull = cs >> 3;
        for (int q = 0; q < nfull; ++q) {
            int s = __shfl(sv[k], 8 * q + grp);
            float dn = __shfl(dnv[k], 8 * q + grp);
            uint4 v = *(const uint4*)(hs_bf + ((size_t)s << 6) + 8 * w8);
            a0 = fmaf(dn, lo16f(v.x), a0); a1 = fmaf(dn, hi16f(v.x), a1);
            a2 = fmaf(dn, lo16f(v.y), a2); a3 = fmaf(dn, hi16f(v.y), a3);
            a4 = fmaf(dn, lo16f(v.z), a4); a5 = fmaf(dn, hi16f(v.z), a5);
            a6 = fmaf(dn, lo16f(v.w), a6); a7 = fmaf(dn, hi16f(v.w), a7);
        }
        int rm = cs & 7;
        if (rm) {
            int e = 8 * nfull + grp;
            int idx = (e < SLAB) ? e : 0;
            float wt = (grp < rm) ? 1.f : 0.f;
            int s = __shfl(sv[k], idx);
            float dn = wt * __shfl(dnv[k], idx);
            uint4 v = *(const uint4*)(hs_bf + ((size_t)s << 6) + 8 * w8);
            a0 = fmaf(dn, lo16f(v.x), a0); a1 = fmaf(dn, hi16f(v.x), a1);
            a2 = fmaf(dn, lo16f(v.y), a2); a3 = fmaf(dn, hi16f(v.y), a3);
            a4 = fmaf(dn, lo16f(v.z), a4); a5 = fmaf(dn, hi16f(v.z), a5);
            a6 = fmaf(dn, lo16f(v.w), a6); a7 = fmaf(dn, hi16f(v.w), a7);
        }
        if (c[k] > SLAB) {
            // rare: scan overflow list; entry i handled by edge-group (i&7)
            for (int i = 0; i < novf; ++i) {
                if (ovf[2 * i] == node && grp == (i & 7)) {
                    int s2 = ovf[2 * i + 1];
                    float dn2 = rsqrtf((float)cursor[s2] + 1.0f);
                    uint4 v = *(const uint4*)(hs_bf + ((size_t)s2 << 6) + 8 * w8);
                    a0 = fmaf(dn2, lo16f(v.x), a0); a1 = fmaf(dn2, hi16f(v.x), a1);
                    a2 = fmaf(dn2, lo16f(v.y), a2); a3 = fmaf(dn2, hi16f(v.y), a3);
                    a4 = fmaf(dn2, lo16f(v.z), a4); a5 = fmaf(dn2, hi16f(v.z), a5);
                    a6 = fmaf(dn2, lo16f(v.w), a6); a7 = fmaf(dn2, hi16f(v.w), a7);
                }
            }
        }
        #define RED(A) A += __shfl_xor(A, 8); A += __shfl_xor(A, 16); A += __shfl_xor(A, 32);
        RED(a0) RED(a1) RED(a2) RED(a3) RED(a4) RED(a5) RED(a6) RED(a7)
        #undef RED
        if (lane < 8) {
            uint4 pk;
            pk.x = (unsigned)f2bf(a0) | ((unsigned)f2bf(a1) << 16);
            pk.y = (unsigned)f2bf(a2) | ((unsigned)f2bf(a3) << 16);
            pk.z = (unsigned)f2bf(a4) | ((unsigned)f2bf(a5) << 16);
            pk.w = (unsigned)f2bf(a6) | ((unsigned)f2bf(a7) << 16);
            *(uint4*)(h_bf + ((size_t)node << 6) + 8 * w8) = pk;
        }
    }
}

// ---- out GEMM: h = relu(dinv*hsum + b1); out = [h@Wmu^T+bmu ; h@Wlv^T+blv] ----
__global__ __launch_bounds__(256) void k_out(const unsigned short* __restrict__ h_bf,
                                             const int* __restrict__ cursor,
                                             const float* __restrict__ b1,
                                             const float* __restrict__ Wmu,
                                             const float* __restrict__ bmu,
                                             const float* __restrict__ Wlv,
                                             const float* __restrict__ blv,
                                             float* __restrict__ out, int n) {
    __shared__ float4 xs[64 * 16];   // activated h tile (16 KB)
    __shared__ uint2 wsb[128 * 16];  // packed-bf16 [Wmu;Wlv] (16 KB)
    int t = threadIdx.x;
    int ty = t >> 4;
    int tx = t & 15;
    int nodeBase = blockIdx.x * 64;

    #pragma unroll
    for (int i = 0; i < 8; ++i) {
        int e = t + i * 256;  // 0..2047
        int r = e >> 4, c4 = e & 15;
        const float4* Wr = (r < 64) ? ((const float4*)Wmu + r * 16)
                                    : ((const float4*)Wlv + (r - 64) * 16);
        float4 wv = Wr[c4];
        uint2 pk;
        pk.x = (unsigned)f2bf(wv.x) | ((unsigned)f2bf(wv.y) << 16);
        pk.y = (unsigned)f2bf(wv.z) | ((unsigned)f2bf(wv.w) << 16);
        wsb[r * 16 + (c4 ^ (r & 15))] = pk;
    }
    int limf4 = (n - nodeBase) * (HDIM / 4);
    #pragma unroll
    for (int i = 0; i < 4; ++i) {
        int f = t + i * 256;
        int r = f >> 4, c4 = f & 15;
        float4 v = make_float4(0.f, 0.f, 0.f, 0.f);
        if (f < limf4) {
            uint2 hv = *(const uint2*)(h_bf + (size_t)nodeBase * HDIM + 4 * (size_t)f);
            float dn = rsqrtf((float)cursor[nodeBase + r] + 1.0f);
            float4 bb = ((const float4*)b1)[c4];
            v.x = fmaxf(fmaf(lo16f(hv.x), dn, bb.x), 0.f);
            v.y = fmaxf(fmaf(hi16f(hv.x), dn, bb.y), 0.f);
            v.z = fmaxf(fmaf(lo16f(hv.y), dn, bb.z), 0.f);
            v.w = fmaxf(fmaf(hi16f(hv.y), dn, bb.w), 0.f);
        }
        xs[r * 16 + (c4 ^ (r & 15))] = v;
    }
    float bias[8];
    #pragma unroll
    for (int j = 0; j < 8; ++j) {
        int o = tx + 16 * j;
        bias[j] = (o < 64) ? bmu[o] : blv[o - 64];
    }
    __syncthreads();

    float acc[4][8] = {};
    #pragma unroll 4
    for (int k4 = 0; k4 < 16; ++k4) {
        float4 xa[4];
        #pragma unroll
        for (int i = 0; i < 4; ++i) {
            int r = ty + 16 * i;
            xa[i] = xs[r * 16 + (k4 ^ (r & 15))];
        }
        #pragma unroll
        for (int j = 0; j < 8; ++j) {
            int r = tx + 16 * j;
            uint2 wv = wsb[r * 16 + (k4 ^ (r & 15))];
            float w0 = lo16f(wv.x), w1 = hi16f(wv.x);
            float w2 = lo16f(wv.y), w3 = hi16f(wv.y);
            #pragma unroll
            for (int i = 0; i < 4; ++i)
                acc[i][j] += xa[i].x * w0 + xa[i].y * w1 + xa[i].z * w2 + xa[i].w * w3;
        }
    }
    #pragma unroll
    for (int i = 0; i < 4; ++i) {
        int node = nodeBase + ty + 16 * i;
        if (node < n) {
            #pragma unroll
            for (int j = 0; j < 8; ++j) {
                int o = tx + 16 * j;
                float val = acc[i][j] + bias[j];
                if (o < 64)
                    out[(size_t)node * HDIM + o] = val;
                else
                    out[(size_t)n * HDIM + (size_t)node * HDIM + (o - 64)] = val;
            }
        }
    }
}

extern "C" void kernel_launch(void* const* d_in, const int* in_sizes, int n_in,
                              void* d_out, int out_size, void* d_ws, size_t ws_size,
                              hipStream_t stream) {
    const float* x   = (const float*)d_in[0];
    const int*   ei  = (const int*)d_in[1];
    const float* W1  = (const float*)d_in[2];
    const float* b1  = (const float*)d_in[3];
    const float* Wmu = (const float*)d_in[4];
    const float* bmu = (const float*)d_in[5];
    const float* Wlv = (const float*)d_in[6];
    const float* blv = (const float*)d_in[7];
    float* out = (float*)d_out;

    const int N = in_sizes[0] / DIN;   // 100000
    const int E = in_sizes[1] / 2;     // 1000000
    const int* src = ei;
    const int* dst = ei + E;

    auto align256 = [](size_t b) { return (b + 255) & ~(size_t)255; };
    char* ws = (char*)d_ws;
    size_t off = 0;
    int* cursor = (int*)(ws + off); off += align256((size_t)N * 4);
    int* govf   = (int*)(ws + off); off += 256;
    int* slab   = (int*)(ws + off); off += align256((size_t)N * SLAB * 4);
    int* ovf    = (int*)(ws + off); off += align256((size_t)OVF_CAP * 2 * 4);
    unsigned short* hs_bf = (unsigned short*)(ws + off);
    off += align256((size_t)N * HDIM * 2);
    unsigned short* h_bf = (unsigned short*)(ws + off);
    off += align256((size_t)N * HDIM * 2);

    hipMemsetAsync(cursor, 0, align256((size_t)N * 4) + 256, stream);

    int scBlocks = (E + 2047) / 2048;      // 489
    int gBlocks  = (N + 63) / 64;          // 1563
    int cycles = max(scBlocks, (gBlocks + 2) / 3);  // 521
    k_front<<<cycles * 4, 256, 0, stream>>>(src, dst, cursor, slab, ovf, govf,
                                            E, scBlocks, x, W1, hs_bf, N, gBlocks);
    k_gather<<<(N + 31) / 32, 256, 0, stream>>>(cursor, slab, hs_bf, govf, ovf,
                                                h_bf, N);
    k_out<<<(N + 63) / 64, 256, 0, stream>>>(h_bf, cursor, b1, Wmu, bmu, Wlv, blv,
                                             out, N);
}

// Round 15
// 155.253 us; speedup vs baseline: 7.1897x; 7.1897x over previous
//
#include <hip/hip_runtime.h>

#define DIN 128
#define HDIM 64
#define SLAB 32
#define OVF_CAP 65536

__device__ __forceinline__ unsigned short f2bf(float f) {
    unsigned u = __float_as_uint(f);
    unsigned r = (u + 0x7fffu + ((u >> 16) & 1u)) >> 16;
    return (unsigned short)r;
}
__device__ __forceinline__ float lo16f(unsigned v) { return __uint_as_float(v << 16); }
__device__ __forceinline__ float hi16f(unsigned v) { return __uint_as_float(v & 0xffff0000u); }

// ---- fused front, parity-interleaved roles: 5 of every 13 blocks scatter
//      (1024 edges each, EPT=4), 8 of every 13 do a 64-node h1 GEMM tile.
//      (R12-proven: 73 us, 44 VGPR. Do not grow either branch.)
__global__ __launch_bounds__(256) void k_front(
        const int* __restrict__ src, const int* __restrict__ dst,
        int* __restrict__ cursor, int* __restrict__ slab,
        int* __restrict__ ovf, int* __restrict__ govf, int E, int scBlocks,
        const float* __restrict__ x, const float* __restrict__ W1,
        unsigned short* __restrict__ hs_bf, int n, int gBlocks) {
    __shared__ float4 xs[64 * 16];
    __shared__ float4 ws[64 * 16];
    int t = threadIdx.x;
    int cyc = blockIdx.x / 13, r = blockIdx.x % 13;

    if (r < 5) {
        // ---------- scatter role ----------
        int sid = cyc * 5 + r;
        if (sid >= scBlocks) return;
        int ebase = sid * 1024 + t;
        int d[4], s[4], p[4];
        bool ok[4];
        #pragma unroll
        for (int q = 0; q < 4; ++q) {
            int e = ebase + q * 256;
            ok[q] = e < E;
            d[q] = ok[q] ? dst[e] : 0;
            s[q] = ok[q] ? src[e] : 0;
        }
        #pragma unroll
        for (int q = 0; q < 4; ++q)
            if (ok[q]) p[q] = atomicAdd(&cursor[d[q]], 1);
        #pragma unroll
        for (int q = 0; q < 4; ++q) {
            if (ok[q]) {
                if (p[q] < SLAB) {
                    slab[(size_t)d[q] * SLAB + p[q]] = s[q];
                } else {
                    int o = atomicAdd(govf, 1);
                    if (o < OVF_CAP) { ovf[2 * o] = d[q]; ovf[2 * o + 1] = s[q]; }
                }
            }
        }
        return;
    }

    // ---------- h1 GEMM role (unscaled): hs_bf = bf16(x @ W1^T) ----------
    int gid = cyc * 8 + (r - 5);
    if (gid >= gBlocks) return;
    int ty = t >> 4, tx = t & 15;
    int nodeBase = gid * 64;
    const float4* W14 = (const float4*)W1;
    const float4* x4 = (const float4*)(x + (size_t)nodeBase * DIN);
    int limf4 = (n - nodeBase) * (DIN / 4);

    float acc[4][4] = {};
    #pragma unroll
    for (int c = 0; c < 2; ++c) {
        if (c) __syncthreads();
        #pragma unroll
        for (int i = 0; i < 4; ++i) {
            int e = t + i * 256;
            int rr = e >> 4, c4 = e & 15;
            int f4 = rr * 32 + c * 16 + c4;
            ws[rr * 16 + (c4 ^ (rr & 15))] = W14[f4];
            float4 v = make_float4(0.f, 0.f, 0.f, 0.f);
            if (f4 < limf4) v = x4[f4];
            xs[rr * 16 + (c4 ^ (rr & 15))] = v;
        }
        __syncthreads();
        #pragma unroll 8
        for (int k4 = 0; k4 < 16; ++k4) {
            float4 xa[4], wb[4];
            #pragma unroll
            for (int i = 0; i < 4; ++i) {
                int rr = ty + 16 * i;
                xa[i] = xs[rr * 16 + (k4 ^ (rr & 15))];
            }
            #pragma unroll
            for (int j = 0; j < 4; ++j) {
                int rr = tx + 16 * j;
                wb[j] = ws[rr * 16 + (k4 ^ (rr & 15))];
            }
            #pragma unroll
            for (int i = 0; i < 4; ++i)
                #pragma unroll
                for (int j = 0; j < 4; ++j)
                    acc[i][j] += xa[i].x * wb[j].x + xa[i].y * wb[j].y +
                                 xa[i].z * wb[j].z + xa[i].w * wb[j].w;
        }
    }
    #pragma unroll
    for (int i = 0; i < 4; ++i) {
        int node = nodeBase + ty + 16 * i;
        if (node < n) {
            #pragma unroll
            for (int j = 0; j < 4; ++j)
                hs_bf[(size_t)node * HDIM + tx + 16 * j] = f2bf(acc[i][j]);
        }
    }
}

// ---- gather, Phase-A/B hoisted: 8 independent slab loads, 8 independent
//      degree gathers, then accumulation. Per-edge dinv, bf16 h output. ----
__global__ __launch_bounds__(256) void k_gather(const int* __restrict__ cursor,
                                                const int* __restrict__ slab,
                                                const unsigned short* __restrict__ hs_bf,
                                                unsigned short* __restrict__ h_bf, int n) {
    int tid = threadIdx.x;
    int lane = tid & 63, wave = tid >> 6;
    int grp = lane >> 3;   // edge slot within octet
    int w8 = lane & 7;     // feature octet
    const int NPW = 8;
    int base = blockIdx.x * (4 * NPW) + wave * NPW;

    // Phase A: independent degree + slab-row loads for all 8 nodes
    int c[NPW], sv[NPW];
    #pragma unroll
    for (int k = 0; k < NPW; ++k) {
        int node = base + k;
        bool valid = node < n;
        c[k] = valid ? cursor[node] : 0;
        int cs = (c[k] < SLAB) ? c[k] : SLAB;
        sv[k] = (valid && lane < cs) ? slab[(size_t)node * SLAB + lane] : 0;
    }
    // Phase B: independent per-edge source-degree gathers
    float dnv[NPW];
    #pragma unroll
    for (int k = 0; k < NPW; ++k) {
        int cs = (c[k] < SLAB) ? c[k] : SLAB;
        dnv[k] = (lane < cs) ? rsqrtf((float)cursor[sv[k]] + 1.0f) : 0.f;
    }
    // Phase C: per-node accumulation
    #pragma unroll
    for (int k = 0; k < NPW; ++k) {
        int node = base + k;
        if (node >= n) break;
        int cs = (c[k] < SLAB) ? c[k] : SLAB;
        float dni = rsqrtf((float)c[k] + 1.0f);
        uint4 v0 = *(const uint4*)(hs_bf + ((size_t)node << 6) + 8 * w8);
        float sw = (grp == 0) ? dni : 0.f;
        float a0 = sw * lo16f(v0.x), a1 = sw * hi16f(v0.x);
        float a2 = sw * lo16f(v0.y), a3 = sw * hi16f(v0.y);
        float a4 = sw * lo16f(v0.z), a5 = sw * hi16f(v0.z);
        float a6 = sw * lo16f(v0.w), a7 = sw * hi16f(v0.w);
        int nfull = cs >> 3;
        for (int q = 0; q < nfull; ++q) {
            int s = __shfl(sv[k], 8 * q + grp);
            float dn = __shfl(dnv[k], 8 * q + grp);
            uint4 v = *(const uint4*)(hs_bf + ((size_t)s << 6) + 8 * w8);
            a0 = fmaf(dn, lo16f(v.x), a0); a1 = fmaf(dn, hi16f(v.x), a1);
            a2 = fmaf(dn, lo16f(v.y), a2); a3 = fmaf(dn, hi16f(v.y), a3);
            a4 = fmaf(dn, lo16f(v.z), a4); a5 = fmaf(dn, hi16f(v.z), a5);
            a6 = fmaf(dn, lo16f(v.w), a6); a7 = fmaf(dn, hi16f(v.w), a7);
        }
        int rm = cs & 7;
        if (rm) {
            int e = 8 * nfull + grp;
            int idx = (e < SLAB) ? e : 0;
            float wt = (grp < rm) ? 1.f : 0.f;
            int s = __shfl(sv[k], idx);
            float dn = wt * __shfl(dnv[k], idx);
            uint4 v = *(const uint4*)(hs_bf + ((size_t)s << 6) + 8 * w8);
            a0 = fmaf(dn, lo16f(v.x), a0); a1 = fmaf(dn, hi16f(v.x), a1);
            a2 = fmaf(dn, lo16f(v.y), a2); a3 = fmaf(dn, hi16f(v.y), a3);
            a4 = fmaf(dn, lo16f(v.z), a4); a5 = fmaf(dn, hi16f(v.z), a5);
            a6 = fmaf(dn, lo16f(v.w), a6); a7 = fmaf(dn, hi16f(v.w), a7);
        }
        #define RED(A) A += __shfl_xor(A, 8); A += __shfl_xor(A, 16); A += __shfl_xor(A, 32);
        RED(a0) RED(a1) RED(a2) RED(a3) RED(a4) RED(a5) RED(a6) RED(a7)
        #undef RED
        if (lane < 8) {
            uint4 pk;
            pk.x = (unsigned)f2bf(a0) | ((unsigned)f2bf(a1) << 16);
            pk.y = (unsigned)f2bf(a2) | ((unsigned)f2bf(a3) << 16);
            pk.z = (unsigned)f2bf(a4) | ((unsigned)f2bf(a5) << 16);
            pk.w = (unsigned)f2bf(a6) | ((unsigned)f2bf(a7) << 16);
            *(uint4*)(h_bf + ((size_t)node << 6) + 8 * w8) = pk;
        }
    }
}

// ---- rare overflow (deg > SLAB): single wave, serial, race-free ----
__global__ __launch_bounds__(64) void k_overflow(const int* __restrict__ govf,
                                                 const int* __restrict__ ovf,
                                                 const int* __restrict__ cursor,
                                                 const unsigned short* __restrict__ hs_bf,
                                                 unsigned short* __restrict__ h_bf) {
    int novf = govf[0];
    if (novf > OVF_CAP) novf = OVF_CAP;
    int lane = threadIdx.x;
    for (int i = 0; i < novf; ++i) {
        int d = ovf[2 * i], s = ovf[2 * i + 1];
        float dn = rsqrtf((float)cursor[s] + 1.0f);
        float hv = lo16f((unsigned)h_bf[(size_t)d * HDIM + lane]);
        float av = lo16f((unsigned)hs_bf[(size_t)s * HDIM + lane]);
        h_bf[(size_t)d * HDIM + lane] = f2bf(fmaf(dn, av, hv));
    }
}

// ---- out GEMM: h = relu(dinv*hsum + b1); out = [h@Wmu^T+bmu ; h@Wlv^T+blv] ----
__global__ __launch_bounds__(256) void k_out(const unsigned short* __restrict__ h_bf,
                                             const int* __restrict__ cursor,
                                             const float* __restrict__ b1,
                                             const float* __restrict__ Wmu,
                                             const float* __restrict__ bmu,
                                             const float* __restrict__ Wlv,
                                             const float* __restrict__ blv,
                                             float* __restrict__ out, int n) {
    __shared__ float4 xs[64 * 16];   // activated h tile (16 KB)
    __shared__ uint2 wsb[128 * 16];  // packed-bf16 [Wmu;Wlv] (16 KB)
    int t = threadIdx.x;
    int ty = t >> 4;
    int tx = t & 15;
    int nodeBase = blockIdx.x * 64;

    #pragma unroll
    for (int i = 0; i < 8; ++i) {
        int e = t + i * 256;  // 0..2047
        int r = e >> 4, c4 = e & 15;
        const float4* Wr = (r < 64) ? ((const float4*)Wmu + r * 16)
                                    : ((const float4*)Wlv + (r - 64) * 16);
        float4 wv = Wr[c4];
        uint2 pk;
        pk.x = (unsigned)f2bf(wv.x) | ((unsigned)f2bf(wv.y) << 16);
        pk.y = (unsigned)f2bf(wv.z) | ((unsigned)f2bf(wv.w) << 16);
        wsb[r * 16 + (c4 ^ (r & 15))] = pk;
    }
    int limf4 = (n - nodeBase) * (HDIM / 4);
    #pragma unroll
    for (int i = 0; i < 4; ++i) {
        int f = t + i * 256;
        int r = f >> 4, c4 = f & 15;
        float4 v = make_float4(0.f, 0.f, 0.f, 0.f);
        if (f < limf4) {
            uint2 hv = *(const uint2*)(h_bf + (size_t)nodeBase * HDIM + 4 * (size_t)f);
            float dn = rsqrtf((float)cursor[nodeBase + r] + 1.0f);
            float4 bb = ((const float4*)b1)[c4];
            v.x = fmaxf(fmaf(lo16f(hv.x), dn, bb.x), 0.f);
            v.y = fmaxf(fmaf(hi16f(hv.x), dn, bb.y), 0.f);
            v.z = fmaxf(fmaf(lo16f(hv.y), dn, bb.z), 0.f);
            v.w = fmaxf(fmaf(hi16f(hv.y), dn, bb.w), 0.f);
        }
        xs[r * 16 + (c4 ^ (r & 15))] = v;
    }
    float bias[8];
    #pragma unroll
    for (int j = 0; j < 8; ++j) {
        int o = tx + 16 * j;
        bias[j] = (o < 64) ? bmu[o] : blv[o - 64];
    }
    __syncthreads();

    float acc[4][8] = {};
    #pragma unroll 4
    for (int k4 = 0; k4 < 16; ++k4) {
        float4 xa[4];
        #pragma unroll
        for (int i = 0; i < 4; ++i) {
            int r = ty + 16 * i;
            xa[i] = xs[r * 16 + (k4 ^ (r & 15))];
        }
        #pragma unroll
        for (int j = 0; j < 8; ++j) {
            int r = tx + 16 * j;
            uint2 wv = wsb[r * 16 + (k4 ^ (r & 15))];
            float w0 = lo16f(wv.x), w1 = hi16f(wv.x);
            float w2 = lo16f(wv.y), w3 = hi16f(wv.y);
            #pragma unroll
            for (int i = 0; i < 4; ++i)
                acc[i][j] += xa[i].x * w0 + xa[i].y * w1 + xa[i].z * w2 + xa[i].w * w3;
        }
    }
    #pragma unroll
    for (int i = 0; i < 4; ++i) {
        int node = nodeBase + ty + 16 * i;
        if (node < n) {
            #pragma unroll
            for (int j = 0; j < 8; ++j) {
                int o = tx + 16 * j;
                float val = acc[i][j] + bias[j];
                if (o < 64)
                    out[(size_t)node * HDIM + o] = val;
                else
                    out[(size_t)n * HDIM + (size_t)node * HDIM + (o - 64)] = val;
            }
        }
    }
}

extern "C" void kernel_launch(void* const* d_in, const int* in_sizes, int n_in,
                              void* d_out, int out_size, void* d_ws, size_t ws_size,
                              hipStream_t stream) {
    const float* x   = (const float*)d_in[0];
    const int*   ei  = (const int*)d_in[1];
    const float* W1  = (const float*)d_in[2];
    const float* b1  = (const float*)d_in[3];
    const float* Wmu = (const float*)d_in[4];
    const float* bmu = (const float*)d_in[5];
    const float* Wlv = (const float*)d_in[6];
    const float* blv = (const float*)d_in[7];
    float* out = (float*)d_out;

    const int N = in_sizes[0] / DIN;   // 100000
    const int E = in_sizes[1] / 2;     // 1000000
    const int* src = ei;
    const int* dst = ei + E;

    auto align256 = [](size_t b) { return (b + 255) & ~(size_t)255; };
    char* ws = (char*)d_ws;
    size_t off = 0;
    int* cursor = (int*)(ws + off); off += align256((size_t)N * 4);
    int* govf   = (int*)(ws + off); off += 256;
    int* slab   = (int*)(ws + off); off += align256((size_t)N * SLAB * 4);
    int* ovf    = (int*)(ws + off); off += align256((size_t)OVF_CAP * 2 * 4);
    unsigned short* hs_bf = (unsigned short*)(ws + off);
    off += align256((size_t)N * HDIM * 2);
    unsigned short* h_bf = (unsigned short*)(ws + off);
    off += align256((size_t)N * HDIM * 2);

    hipMemsetAsync(cursor, 0, align256((size_t)N * 4) + 256, stream);

    int scBlocks = (E + 1023) / 1024;      // 977
    int gBlocks  = (N + 63) / 64;          // 1563
    int cycles = max((scBlocks + 4) / 5, (gBlocks + 7) / 8);  // 196
    k_front<<<cycles * 13, 256, 0, stream>>>(src, dst, cursor, slab, ovf, govf,
                                             E, scBlocks, x, W1, hs_bf, N, gBlocks);
    k_gather<<<(N + 31) / 32, 256, 0, stream>>>(cursor, slab, hs_bf, h_bf, N);
    k_overflow<<<1, 64, 0, stream>>>(govf, ovf, cursor, hs_bf, h_bf);
    k_out<<<(N + 63) / 64, 256, 0, stream>>>(h_bf, cursor, b1, Wmu, bmu, Wlv, blv,
                                             out, N);
}

// Round 18
// 148.540 us; speedup vs baseline: 7.5146x; 1.0452x over previous
//
#include <hip/hip_runtime.h>

#define DIN 128
#define HDIM 64
#define SLAB 32
#define OVF_CAP 65536

__device__ __forceinline__ unsigned short f2bf(float f) {
    unsigned u = __float_as_uint(f);
    unsigned r = (u + 0x7fffu + ((u >> 16) & 1u)) >> 16;
    return (unsigned short)r;
}
__device__ __forceinline__ float lo16f(unsigned v) { return __uint_as_float(v << 16); }
__device__ __forceinline__ float hi16f(unsigned v) { return __uint_as_float(v & 0xffff0000u); }

// ---- fused front, parity 4:9 — r<4: scatter 1536 edges (EPT=6);
//      else: 64-node h1 GEMM tile (R12-proven GEMM branch, unchanged). ----
__global__ __launch_bounds__(256) void k_front(
        const int* __restrict__ src, const int* __restrict__ dst,
        int* __restrict__ cursor, int* __restrict__ slab,
        int* __restrict__ ovf, int* __restrict__ govf, int E, int scBlocks,
        const float* __restrict__ x, const float* __restrict__ W1,
        unsigned short* __restrict__ hs_bf, int n, int gBlocks) {
    __shared__ float4 xs[64 * 16];
    __shared__ float4 ws[64 * 16];
    int t = threadIdx.x;
    int cyc = blockIdx.x / 13, r = blockIdx.x % 13;

    if (r < 4) {
        // ---------- scatter role: 6 edges/thread ----------
        int sid = cyc * 4 + r;
        if (sid >= scBlocks) return;
        int ebase = sid * 1536 + t;
        int d[6], s[6], p[6];
        bool ok[6];
        #pragma unroll
        for (int q = 0; q < 6; ++q) {
            int e = ebase + q * 256;
            ok[q] = e < E;
            d[q] = ok[q] ? dst[e] : 0;
            s[q] = ok[q] ? src[e] : 0;
        }
        #pragma unroll
        for (int q = 0; q < 6; ++q)
            if (ok[q]) p[q] = atomicAdd(&cursor[d[q]], 1);
        #pragma unroll
        for (int q = 0; q < 6; ++q) {
            if (ok[q]) {
                if (p[q] < SLAB) {
                    slab[(size_t)d[q] * SLAB + p[q]] = s[q];
                } else {
                    int o = atomicAdd(govf, 1);
                    if (o < OVF_CAP) { ovf[2 * o] = d[q]; ovf[2 * o + 1] = s[q]; }
                }
            }
        }
        return;
    }

    // ---------- h1 GEMM role (unscaled): hs_bf = bf16(x @ W1^T) ----------
    int gid = cyc * 9 + (r - 4);
    if (gid >= gBlocks) return;
    int ty = t >> 4, tx = t & 15;
    int nodeBase = gid * 64;
    const float4* W14 = (const float4*)W1;
    const float4* x4 = (const float4*)(x + (size_t)nodeBase * DIN);
    int limf4 = (n - nodeBase) * (DIN / 4);

    float acc[4][4] = {};
    #pragma unroll
    for (int c = 0; c < 2; ++c) {
        if (c) __syncthreads();
        #pragma unroll
        for (int i = 0; i < 4; ++i) {
            int e = t + i * 256;
            int rr = e >> 4, c4 = e & 15;
            int f4 = rr * 32 + c * 16 + c4;
            ws[rr * 16 + (c4 ^ (rr & 15))] = W14[f4];
            float4 v = make_float4(0.f, 0.f, 0.f, 0.f);
            if (f4 < limf4) v = x4[f4];
            xs[rr * 16 + (c4 ^ (rr & 15))] = v;
        }
        __syncthreads();
        #pragma unroll 8
        for (int k4 = 0; k4 < 16; ++k4) {
            float4 xa[4], wb[4];
            #pragma unroll
            for (int i = 0; i < 4; ++i) {
                int rr = ty + 16 * i;
                xa[i] = xs[rr * 16 + (k4 ^ (rr & 15))];
            }
            #pragma unroll
            for (int j = 0; j < 4; ++j) {
                int rr = tx + 16 * j;
                wb[j] = ws[rr * 16 + (k4 ^ (rr & 15))];
            }
            #pragma unroll
            for (int i = 0; i < 4; ++i)
                #pragma unroll
                for (int j = 0; j < 4; ++j)
                    acc[i][j] += xa[i].x * wb[j].x + xa[i].y * wb[j].y +
                                 xa[i].z * wb[j].z + xa[i].w * wb[j].w;
        }
    }
    #pragma unroll
    for (int i = 0; i < 4; ++i) {
        int node = nodeBase + ty + 16 * i;
        if (node < n) {
            #pragma unroll
            for (int j = 0; j < 4; ++j)
                hs_bf[(size_t)node * HDIM + tx + 16 * j] = f2bf(acc[i][j]);
        }
    }
}

// ---- gather (R12-exact): per-edge dinv, bf16 h output ----
__global__ __launch_bounds__(256) void k_gather(const int* __restrict__ cursor,
                                                const int* __restrict__ slab,
                                                const unsigned short* __restrict__ hs_bf,
                                                unsigned short* __restrict__ h_bf, int n) {
    int tid = threadIdx.x;
    int lane = tid & 63, wave = tid >> 6;
    int grp = lane >> 3;   // edge slot within octet
    int w8 = lane & 7;     // feature octet
    const int NPW = 8;
    int base = blockIdx.x * (4 * NPW) + wave * NPW;
    for (int nn = 0; nn < NPW; ++nn) {
        int node = base + nn;
        if (node >= n) break;
        int c = cursor[node];
        int cs = (c < SLAB) ? c : SLAB;
        int sv = 0;
        float dnv = 0.f;
        if (lane < cs) {
            sv = slab[(size_t)node * SLAB + lane];
            dnv = rsqrtf((float)cursor[sv] + 1.0f);
        }
        float dni = rsqrtf((float)c + 1.0f);
        uint4 v0 = *(const uint4*)(hs_bf + ((size_t)node << 6) + 8 * w8);
        float sw = (grp == 0) ? dni : 0.f;
        float a0 = sw * lo16f(v0.x), a1 = sw * hi16f(v0.x);
        float a2 = sw * lo16f(v0.y), a3 = sw * hi16f(v0.y);
        float a4 = sw * lo16f(v0.z), a5 = sw * hi16f(v0.z);
        float a6 = sw * lo16f(v0.w), a7 = sw * hi16f(v0.w);
        int nfull = cs >> 3;
        for (int q = 0; q < nfull; ++q) {
            int s = __shfl(sv, 8 * q + grp);
            float dn = __shfl(dnv, 8 * q + grp);
            uint4 v = *(const uint4*)(hs_bf + ((size_t)s << 6) + 8 * w8);
            a0 = fmaf(dn, lo16f(v.x), a0); a1 = fmaf(dn, hi16f(v.x), a1);
            a2 = fmaf(dn, lo16f(v.y), a2); a3 = fmaf(dn, hi16f(v.y), a3);
            a4 = fmaf(dn, lo16f(v.z), a4); a5 = fmaf(dn, hi16f(v.z), a5);
            a6 = fmaf(dn, lo16f(v.w), a6); a7 = fmaf(dn, hi16f(v.w), a7);
        }
        int rm = cs & 7;
        if (rm) {
            int e = 8 * nfull + grp;
            int idx = (e < SLAB) ? e : 0;
            float wt = (grp < rm) ? 1.f : 0.f;
            int s = __shfl(sv, idx);
            float dn = wt * __shfl(dnv, idx);
            uint4 v = *(const uint4*)(hs_bf + ((size_t)s << 6) + 8 * w8);
            a0 = fmaf(dn, lo16f(v.x), a0); a1 = fmaf(dn, hi16f(v.x), a1);
            a2 = fmaf(dn, lo16f(v.y), a2); a3 = fmaf(dn, hi16f(v.y), a3);
            a4 = fmaf(dn, lo16f(v.z), a4); a5 = fmaf(dn, hi16f(v.z), a5);
            a6 = fmaf(dn, lo16f(v.w), a6); a7 = fmaf(dn, hi16f(v.w), a7);
        }
        #define RED(A) A += __shfl_xor(A, 8); A += __shfl_xor(A, 16); A += __shfl_xor(A, 32);
        RED(a0) RED(a1) RED(a2) RED(a3) RED(a4) RED(a5) RED(a6) RED(a7)
        #undef RED
        if (lane < 8) {
            uint4 pk;
            pk.x = (unsigned)f2bf(a0) | ((unsigned)f2bf(a1) << 16);
            pk.y = (unsigned)f2bf(a2) | ((unsigned)f2bf(a3) << 16);
            pk.z = (unsigned)f2bf(a4) | ((unsigned)f2bf(a5) << 16);
            pk.w = (unsigned)f2bf(a6) | ((unsigned)f2bf(a7) << 16);
            *(uint4*)(h_bf + ((size_t)node << 6) + 8 * w8) = pk;
        }
    }
}

// ---- rare overflow (deg > SLAB): single wave, serial, race-free ----
__global__ __launch_bounds__(64) void k_overflow(const int* __restrict__ govf,
                                                 const int* __restrict__ ovf,
                                                 const int* __restrict__ cursor,
                                                 const unsigned short* __restrict__ hs_bf,
                                                 unsigned short* __restrict__ h_bf) {
    int novf = govf[0];
    if (novf > OVF_CAP) novf = OVF_CAP;
    int lane = threadIdx.x;
    for (int i = 0; i < novf; ++i) {
        int d = ovf[2 * i], s = ovf[2 * i + 1];
        float dn = rsqrtf((float)cursor[s] + 1.0f);
        float hv = lo16f((unsigned)h_bf[(size_t)d * HDIM + lane]);
        float av = lo16f((unsigned)hs_bf[(size_t)s * HDIM + lane]);
        h_bf[(size_t)d * HDIM + lane] = f2bf(fmaf(dn, av, hv));
    }
}

// ---- out GEMM: h = relu(dinv*hsum + b1); out = [h@Wmu^T+bmu ; h@Wlv^T+blv] ----
__global__ __launch_bounds__(256) void k_out(const unsigned short* __restrict__ h_bf,
                                             const int* __restrict__ cursor,
                                             const float* __restrict__ b1,
                                             const float* __restrict__ Wmu,
                                             const float* __restrict__ bmu,
                                             const float* __restrict__ Wlv,
                                             const float* __restrict__ blv,
                                             float* __restrict__ out, int n) {
    __shared__ float4 xs[64 * 16];   // activated h tile (16 KB)
    __shared__ uint2 wsb[128 * 16];  // packed-bf16 [Wmu;Wlv] (16 KB)
    int t = threadIdx.x;
    int ty = t >> 4;
    int tx = t & 15;
    int nodeBase = blockIdx.x * 64;

    #pragma unroll
    for (int i = 0; i < 8; ++i) {
        int e = t + i * 256;  // 0..2047
        int r = e >> 4, c4 = e & 15;
        const float4* Wr = (r < 64) ? ((const float4*)Wmu + r * 16)
                                    : ((const float4*)Wlv + (r - 64) * 16);
        float4 wv = Wr[c4];
        uint2 pk;
        pk.x = (unsigned)f2bf(wv.x) | ((unsigned)f2bf(wv.y) << 16);
        pk.y = (unsigned)f2bf(wv.z) | ((unsigned)f2bf(wv.w) << 16);
        wsb[r * 16 + (c4 ^ (r & 15))] = pk;
    }
    int limf4 = (n - nodeBase) * (HDIM / 4);
    #pragma unroll
    for (int i = 0; i < 4; ++i) {
        int f = t + i * 256;
        int r = f >> 4, c4 = f & 15;
        float4 v = make_float4(0.f, 0.f, 0.f, 0.f);
        if (f < limf4) {
            uint2 hv = *(const uint2*)(h_bf + (size_t)nodeBase * HDIM + 4 * (size_t)f);
            float dn = rsqrtf((float)cursor[nodeBase + r] + 1.0f);
            float4 bb = ((const float4*)b1)[c4];
            v.x = fmaxf(fmaf(lo16f(hv.x), dn, bb.x), 0.f);
            v.y = fmaxf(fmaf(hi16f(hv.x), dn, bb.y), 0.f);
            v.z = fmaxf(fmaf(lo16f(hv.y), dn, bb.z), 0.f);
            v.w = fmaxf(fmaf(hi16f(hv.y), dn, bb.w), 0.f);
        }
        xs[r * 16 + (c4 ^ (r & 15))] = v;
    }
    float bias[8];
    #pragma unroll
    for (int j = 0; j < 8; ++j) {
        int o = tx + 16 * j;
        bias[j] = (o < 64) ? bmu[o] : blv[o - 64];
    }
    __syncthreads();

    float acc[4][8] = {};
    #pragma unroll 4
    for (int k4 = 0; k4 < 16; ++k4) {
        float4 xa[4];
        #pragma unroll
        for (int i = 0; i < 4; ++i) {
            int r = ty + 16 * i;
            xa[i] = xs[r * 16 + (k4 ^ (r & 15))];
        }
        #pragma unroll
        for (int j = 0; j < 8; ++j) {
            int r = tx + 16 * j;
            uint2 wv = wsb[r * 16 + (k4 ^ (r & 15))];
            float w0 = lo16f(wv.x), w1 = hi16f(wv.x);
            float w2 = lo16f(wv.y), w3 = hi16f(wv.y);
            #pragma unroll
            for (int i = 0; i < 4; ++i)
                acc[i][j] += xa[i].x * w0 + xa[i].y * w1 + xa[i].z * w2 + xa[i].w * w3;
        }
    }
    #pragma unroll
    for (int i = 0; i < 4; ++i) {
        int node = nodeBase + ty + 16 * i;
        if (node < n) {
            #pragma unroll
            for (int j = 0; j < 8; ++j) {
                int o = tx + 16 * j;
                float val = acc[i][j] + bias[j];
                if (o < 64)
                    out[(size_t)node * HDIM + o] = val;
                else
                    out[(size_t)n * HDIM + (size_t)node * HDIM + (o - 64)] = val;
            }
        }
    }
}

extern "C" void kernel_launch(void* const* d_in, const int* in_sizes, int n_in,
                              void* d_out, int out_size, void* d_ws, size_t ws_size,
                              hipStream_t stream) {
    const float* x   = (const float*)d_in[0];
    const int*   ei  = (const int*)d_in[1];
    const float* W1  = (const float*)d_in[2];
    const float* b1  = (const float*)d_in[3];
    const float* Wmu = (const float*)d_in[4];
    const float* bmu = (const float*)d_in[5];
    const float* Wlv = (const float*)d_in[6];
    const float* blv = (const float*)d_in[7];
    float* out = (float*)d_out;

    const int N = in_sizes[0] / DIN;   // 100000
    const int E = in_sizes[1] / 2;     // 1000000
    const int* src = ei;
    const int* dst = ei + E;

    auto align256 = [](size_t b) { return (b + 255) & ~(size_t)255; };
    char* ws = (char*)d_ws;
    size_t off = 0;
    int* cursor = (int*)(ws + off); off += align256((size_t)N * 4);
    int* govf   = (int*)(ws + off); off += 256;
    int* slab   = (int*)(ws + off); off += align256((size_t)N * SLAB * 4);
    int* ovf    = (int*)(ws + off); off += align256((size_t)OVF_CAP * 2 * 4);
    unsigned short* hs_bf = (unsigned short*)(ws + off);
    off += align256((size_t)N * HDIM * 2);
    unsigned short* h_bf = (unsigned short*)(ws + off);
    off += align256((size_t)N * HDIM * 2);

    hipMemsetAsync(cursor, 0, align256((size_t)N * 4) + 256, stream);

    int scBlocks = (E + 1535) / 1536;      // 652
    int gBlocks  = (N + 63) / 64;          // 1563
    int cycles = max((scBlocks + 3) / 4, (gBlocks + 8) / 9);  // 174
    k_front<<<cycles * 13, 256, 0, stream>>>(src, dst, cursor, slab, ovf, govf,
                                             E, scBlocks, x, W1, hs_bf, N, gBlocks);
    k_gather<<<(N + 31) / 32, 256, 0, stream>>>(cursor, slab, hs_bf, h_bf, N);
    k_overflow<<<1, 64, 0, stream>>>(govf, ovf, cursor, hs_bf, h_bf);
    k_out<<<(N + 63) / 64, 256, 0, stream>>>(h_bf, cursor, b1, Wmu, bmu, Wlv, blv,
                                             out, N);
}